// Round 5
// baseline (548.117 us; speedup 1.0000x reference)
//
#include <hip/hip_runtime.h>
#include <math.h>

#define N_NODES 100000
#define N_EDGES 1200000
#define DIM 64
#define SCAN_BLOCKS ((N_NODES + 1023) / 1024)   // 98
#define CSR_CAP (N_EDGES + 7 * N_NODES)          // padded-to-8 worst case: 1.9M entries

struct Edge { int s; float nrm; };               // 8B

// ---------------- degree histogram (int4: 4 edges/thread) ----------------

__global__ void k_count(const int4* __restrict__ dst4, int* __restrict__ cnt) {
    int e = blockIdx.x * blockDim.x + threadIdx.x;
    if (e < N_EDGES / 4) {
        int4 d = dst4[e];
        atomicAdd(&cnt[d.x], 1);
        atomicAdd(&cnt[d.y], 1);
        atomicAdd(&cnt[d.z], 1);
        atomicAdd(&cnt[d.w], 1);
    }
}

// ---------------- 3-phase scan over PADDED counts + dinv ----------------
// Segments padded to multiple of 8 so the gather loop is all-full batches.

__global__ void k_scanA(const int* __restrict__ cnt, int* __restrict__ off,
                        float* __restrict__ dinv, int* __restrict__ bsum) {
    __shared__ int buf[1024];
    int tid = threadIdx.x;
    int i = blockIdx.x * 1024 + tid;
    int v = (i < N_NODES) ? cnt[i] : 0;
    if (i < N_NODES) dinv[i] = rsqrtf((float)(v + 1));   // +1 self-loop
    int vp = (v + 7) & ~7;                               // pad to 8
    buf[tid] = vp;
    __syncthreads();
    for (int ofs = 1; ofs < 1024; ofs <<= 1) {           // Hillis-Steele inclusive
        int t = (tid >= ofs) ? buf[tid - ofs] : 0;
        __syncthreads();
        buf[tid] += t;
        __syncthreads();
    }
    if (i < N_NODES) off[i] = buf[tid] - vp;             // local exclusive (padded)
    if (tid == 1023) bsum[blockIdx.x] = buf[1023];
}

__global__ void k_scanB(int* __restrict__ bsum) {
    __shared__ int buf[128];
    int tid = threadIdx.x;
    int v = (tid < SCAN_BLOCKS) ? bsum[tid] : 0;
    buf[tid] = v;
    __syncthreads();
    for (int ofs = 1; ofs < 128; ofs <<= 1) {
        int t = (tid >= ofs) ? buf[tid - ofs] : 0;
        __syncthreads();
        buf[tid] += t;
        __syncthreads();
    }
    if (tid < SCAN_BLOCKS) bsum[tid] = buf[tid] - v;
}

__global__ void k_scanC(int* __restrict__ off, const int* __restrict__ bsum,
                        int* __restrict__ cur) {
    int i = blockIdx.x * blockDim.x + threadIdx.x;
    if (i < N_NODES) {
        int o = off[i] + bsum[i >> 10];
        off[i] = o;
        cur[i] = o;
    }
}

// ---------------- CSR bucket fill (int4: 4 edges/thread) ----------------
// csr pre-memset to 0, so pad slots have {s=0, nrm=0} -> contribute nothing.

__global__ void k_fill(const int4* __restrict__ src4, const int4* __restrict__ dst4,
                       const float* __restrict__ dinv, int* __restrict__ cur,
                       Edge* __restrict__ csr) {
    int e = blockIdx.x * blockDim.x + threadIdx.x;
    if (e < N_EDGES / 4) {
        int4 s = src4[e];
        int4 d = dst4[e];
        int p0 = atomicAdd(&cur[d.x], 1);
        int p1 = atomicAdd(&cur[d.y], 1);
        int p2 = atomicAdd(&cur[d.z], 1);
        int p3 = atomicAdd(&cur[d.w], 1);
        Edge e0 = {s.x, dinv[s.x] * dinv[d.x]}; csr[p0] = e0;
        Edge e1 = {s.y, dinv[s.y] * dinv[d.y]}; csr[p1] = e1;
        Edge e2 = {s.z, dinv[s.z] * dinv[d.z]}; csr[p2] = e2;
        Edge e3 = {s.w, dinv[s.w] * dinv[d.w]}; csr[p3] = e3;
    }
}

// ---------------- dense h = x @ W (W staged in LDS) ----------------

__global__ void k_gemm(const float* __restrict__ x, const float* __restrict__ W,
                       float* __restrict__ h) {
    __shared__ float Wlds[DIM * DIM];
    int tid = threadIdx.x;
    for (int i = tid * 4; i < DIM * DIM; i += 256 * 4)
        *(float4*)&Wlds[i] = *(const float4*)&W[i];
    __syncthreads();

    int wave = tid >> 6;
    int lane = tid & 63;
    int n0 = (blockIdx.x * 4 + wave) * 8;
    if (n0 >= N_NODES) return;

    float acc[8];
#pragma unroll
    for (int m = 0; m < 8; ++m) acc[m] = 0.f;

    for (int k4 = 0; k4 < DIM / 4; ++k4) {
        float4 xv[8];
#pragma unroll
        for (int m = 0; m < 8; ++m)
            xv[m] = *(const float4*)&x[(size_t)(n0 + m) * DIM + k4 * 4];
#pragma unroll
        for (int kk = 0; kk < 4; ++kk) {
            float wk = Wlds[(k4 * 4 + kk) * DIM + lane];
#pragma unroll
            for (int m = 0; m < 8; ++m) {
                float xs = (kk == 0) ? xv[m].x : (kk == 1) ? xv[m].y
                         : (kk == 2) ? xv[m].z : xv[m].w;
                acc[m] = fmaf(xs, wk, acc[m]);
            }
        }
    }
#pragma unroll
    for (int m = 0; m < 8; ++m)
        h[(size_t)(n0 + m) * DIM + lane] = acc[m];
}

// ---------------- gather: out = relu?( A_hat @ h + b ) ----------------
// One wave per node, lane = column. Zero DS ops; zero per-lane predication.
// Per batch: 4 uniform int4 csr loads (scalar pipe) + 8 independent coalesced
// 256B row gathers in flight.

template <bool RELU_OUT>
__global__ void k_gather(const float* __restrict__ h, const float* __restrict__ dinv,
                         const int* __restrict__ off, const int* __restrict__ cnt,
                         const int4* __restrict__ csr4, const float* __restrict__ b,
                         float* __restrict__ out) {
    int node = __builtin_amdgcn_readfirstlane(blockIdx.x * 4 + (threadIdx.x >> 6));
    if (node >= N_NODES) return;
    const int lane = threadIdx.x & 63;

    int s0 = __builtin_amdgcn_readfirstlane(off[node]);   // multiple of 8
    int n  = __builtin_amdgcn_readfirstlane(cnt[node]);
    int nb = (n + 7) >> 3;

    const int4* p = csr4 + (s0 >> 1);                     // 2 edges per int4
    float acc = 0.f;
    for (int bi = 0; bi < nb; ++bi, p += 4) {
        int4 e0 = p[0];
        int4 e1 = p[1];
        int4 e2 = p[2];
        int4 e3 = p[3];
        float v0 = h[(size_t)e0.x * DIM + lane];
        float v1 = h[(size_t)e0.z * DIM + lane];
        float v2 = h[(size_t)e1.x * DIM + lane];
        float v3 = h[(size_t)e1.z * DIM + lane];
        float v4 = h[(size_t)e2.x * DIM + lane];
        float v5 = h[(size_t)e2.z * DIM + lane];
        float v6 = h[(size_t)e3.x * DIM + lane];
        float v7 = h[(size_t)e3.z * DIM + lane];
        acc = fmaf(v0, __int_as_float(e0.y), acc);
        acc = fmaf(v1, __int_as_float(e0.w), acc);
        acc = fmaf(v2, __int_as_float(e1.y), acc);
        acc = fmaf(v3, __int_as_float(e1.w), acc);
        acc = fmaf(v4, __int_as_float(e2.y), acc);
        acc = fmaf(v5, __int_as_float(e2.w), acc);
        acc = fmaf(v6, __int_as_float(e3.y), acc);
        acc = fmaf(v7, __int_as_float(e3.w), acc);
    }

    // self-loop + bias
    float dd = dinv[node];
    acc = fmaf(h[(size_t)node * DIM + lane], dd * dd, acc + b[lane]);
    if (RELU_OUT) acc = fmaxf(acc, 0.f);
    out[(size_t)node * DIM + lane] = acc;
}

// ---------------- launch ----------------

extern "C" void kernel_launch(void* const* d_in, const int* in_sizes, int n_in,
                              void* d_out, int out_size, void* d_ws, size_t ws_size,
                              hipStream_t stream) {
    const float* x   = (const float*)d_in[0];
    const int*   ei  = (const int*)d_in[1];     // [2, E] row-major
    const float* W1  = (const float*)d_in[2];
    const float* b1  = (const float*)d_in[3];
    const float* W2  = (const float*)d_in[4];
    const float* b2  = (const float*)d_in[5];
    const float* W3  = (const float*)d_in[6];
    const float* b3  = (const float*)d_in[7];
    float* out = (float*)d_out;

    const int4* src4 = (const int4*)ei;
    const int4* dst4 = (const int4*)(ei + N_EDGES);

    // ws layout (256B-aligned)
    char* ws = (char*)d_ws;
    int*   cnt  = (int*)ws;                        // 400 KB
    int*   off  = (int*)(ws + 0x80000);            // 400 KB
    int*   cur  = (int*)(ws + 0x100000);           // 400 KB
    float* dinv = (float*)(ws + 0x180000);         // 400 KB
    int*   bsum = (int*)(ws + 0x1F0000);           // small
    Edge*  csr  = (Edge*)(ws + 0x200000);          // 15.2 MB (padded CSR)
    float* bufA = (float*)(ws + 0x1200000);        // 25.6 MB
    float* bufB = (float*)(ws + 0x1200000 + 0x1A00000);  // 25.6 MB

    // ---- CSR build (once per launch) ----
    hipMemsetAsync(cnt, 0, N_NODES * sizeof(int), stream);
    hipMemsetAsync(csr, 0, (size_t)CSR_CAP * sizeof(Edge), stream);
    k_count<<<(N_EDGES / 4 + 255) / 256, 256, 0, stream>>>(dst4, cnt);
    k_scanA<<<SCAN_BLOCKS, 1024, 0, stream>>>(cnt, off, dinv, bsum);
    k_scanB<<<1, 128, 0, stream>>>(bsum);
    k_scanC<<<(N_NODES + 255) / 256, 256, 0, stream>>>(off, bsum, cur);
    k_fill<<<(N_EDGES / 4 + 255) / 256, 256, 0, stream>>>(src4, dst4, dinv, cur, csr);

    const int gemm_blocks   = (N_NODES + 31) / 32;   // 3125
    const int gather_blocks = (N_NODES + 3) / 4;     // 25000 (1 wave/node)

    // Layer 1
    k_gemm<<<gemm_blocks, 256, 0, stream>>>(x, W1, bufA);
    k_gather<true><<<gather_blocks, 256, 0, stream>>>(bufA, dinv, off, cnt,
                                                      (const int4*)csr, b1, bufB);
    // Layer 2
    k_gemm<<<gemm_blocks, 256, 0, stream>>>(bufB, W2, bufA);
    k_gather<true><<<gather_blocks, 256, 0, stream>>>(bufA, dinv, off, cnt,
                                                      (const int4*)csr, b2, bufB);
    // Layer 3
    k_gemm<<<gemm_blocks, 256, 0, stream>>>(bufB, W3, bufA);
    k_gather<false><<<gather_blocks, 256, 0, stream>>>(bufA, dinv, off, cnt,
                                                       (const int4*)csr, b3, out);
}